// Round 1
// baseline (3760.691 us; speedup 1.0000x reference)
//
#include <hip/hip_runtime.h>
#include <math.h>

// ---------------- problem dims ----------------
static constexpr int B_   = 64;
static constexpr int H0_  = 480, W0_ = 80;
static constexpr int C0_  = 8, C1_ = 16, C2_ = 16, C3_ = 32;
static constexpr int H1_  = 160, W1_ = 40;   // after pool1 (3,2)
static constexpr int T_   = 40,  WP_ = 20;   // after pool2 (4,2)
static constexpr int IG_  = 640;             // 20*32 GRU input
static constexpr int HID_ = 256;
static constexpr int G3_  = 768;             // 3*HID

// out: output (64,40,512) then hidden (2,64,256)
static constexpr int OUT_MAIN_ = B_ * T_ * 2 * HID_;   // 1,310,720

// ---------------- conv0 (1->8) + relu ----------------
__global__ __launch_bounds__(256) void conv0_relu(
    const float* __restrict__ in, const float* __restrict__ w,
    const float* __restrict__ bias, float* __restrict__ out) {
  __shared__ float ws[C0_ * 9];
  if (threadIdx.x < C0_ * 9) ws[threadIdx.x] = w[threadIdx.x];
  __syncthreads();
  int n = blockIdx.x * 256 + threadIdx.x;
  int wi = n % W0_;
  int h  = (n / W0_) % H0_;
  int c  = (n / (W0_ * H0_)) % C0_;
  int b  = n / (W0_ * H0_ * C0_);
  const float* inb = in + b * (H0_ * W0_);
  float s = bias[c];
#pragma unroll
  for (int kh = 0; kh < 3; ++kh) {
    int ih = h + kh - 1;
    if (ih < 0 || ih >= H0_) continue;
#pragma unroll
    for (int kw = 0; kw < 3; ++kw) {
      int iw = wi + kw - 1;
      if (iw < 0 || iw >= W0_) continue;
      s += inb[ih * W0_ + iw] * ws[(c * 3 + kh) * 3 + kw];
    }
  }
  out[n] = fmaxf(s, 0.f);
}

// ---------------- conv1 (8->16) + relu + maxpool(3,2) fused ----------------
__global__ __launch_bounds__(256) void conv1_relu_pool(
    const float* __restrict__ y0, const float* __restrict__ w,
    const float* __restrict__ bias, float* __restrict__ y2) {
  __shared__ float ws[C1_ * C0_ * 9];  // 1152
  for (int i = threadIdx.x; i < C1_ * C0_ * 9; i += 256) ws[i] = w[i];
  __syncthreads();
  int n  = blockIdx.x * 256 + threadIdx.x;
  int ow = n % W1_;
  int oh = (n / W1_) % H1_;
  int c  = (n / (W1_ * H1_)) % C1_;
  int b  = n / (W1_ * H1_ * C1_);
  const float* yb = y0 + b * (C0_ * H0_ * W0_);
  float m = -1e30f;
  for (int ph = 0; ph < 3; ++ph) {
    int h = oh * 3 + ph;
    for (int pw = 0; pw < 2; ++pw) {
      int wq = ow * 2 + pw;
      float s = 0.f;
      for (int ci = 0; ci < C0_; ++ci) {
        const float* yc = yb + ci * (H0_ * W0_);
        const float* wc = ws + (c * C0_ + ci) * 9;
#pragma unroll
        for (int kh = 0; kh < 3; ++kh) {
          int ih = h + kh - 1;
          if (ih < 0 || ih >= H0_) continue;
#pragma unroll
          for (int kw = 0; kw < 3; ++kw) {
            int iw = wq + kw - 1;
            if (iw < 0 || iw >= W0_) continue;
            s += yc[ih * W0_ + iw] * wc[kh * 3 + kw];
          }
        }
      }
      m = fmaxf(m, s);
    }
  }
  y2[n] = fmaxf(m + bias[c], 0.f);  // relu(max(conv)+b) == max(relu(conv+b))
}

// ---------------- conv2 (16->16) + relu ----------------
__global__ __launch_bounds__(256) void conv2_relu(
    const float* __restrict__ y2, const float* __restrict__ w,
    const float* __restrict__ bias, float* __restrict__ y3) {
  __shared__ float ws[C2_ * C1_ * 9];  // 2304
  for (int i = threadIdx.x; i < C2_ * C1_ * 9; i += 256) ws[i] = w[i];
  __syncthreads();
  int n  = blockIdx.x * 256 + threadIdx.x;
  int wi = n % W1_;
  int h  = (n / W1_) % H1_;
  int c  = (n / (W1_ * H1_)) % C2_;
  int b  = n / (W1_ * H1_ * C2_);
  const float* yb = y2 + b * (C1_ * H1_ * W1_);
  float s = bias[c];
  for (int ci = 0; ci < C1_; ++ci) {
    const float* yc = yb + ci * (H1_ * W1_);
    const float* wc = ws + (c * C1_ + ci) * 9;
#pragma unroll
    for (int kh = 0; kh < 3; ++kh) {
      int ih = h + kh - 1;
      if (ih < 0 || ih >= H1_) continue;
#pragma unroll
      for (int kw = 0; kw < 3; ++kw) {
        int iw = wi + kw - 1;
        if (iw < 0 || iw >= W1_) continue;
        s += yc[ih * W1_ + iw] * wc[kh * 3 + kw];
      }
    }
  }
  y3[n] = fmaxf(s, 0.f);
}

// ------- conv3 (16->32) + relu + maxpool(4,2), writes x in (t,b,w,c) -------
__global__ __launch_bounds__(256) void conv3_relu_pool(
    const float* __restrict__ y3, const float* __restrict__ w,
    const float* __restrict__ bias, float* __restrict__ x) {
  __shared__ float ws[C2_ * 9 * C3_];  // transposed: [(ci*3+kh)*3+kw][c], 4608
  for (int i = threadIdx.x; i < C3_ * C2_ * 9; i += 256) {
    int c = i / (C2_ * 9);
    int r = i % (C2_ * 9);
    ws[r * C3_ + c] = w[i];
  }
  __syncthreads();
  int n  = blockIdx.x * 256 + threadIdx.x;
  int c  = n % C3_;
  int wo = (n / C3_) % WP_;
  int b  = (n / (C3_ * WP_)) % B_;
  int t  = n / (C3_ * WP_ * B_);
  const float* yb = y3 + b * (C2_ * H1_ * W1_);
  float m = -1e30f;
  for (int ph = 0; ph < 4; ++ph) {
    int h = t * 4 + ph;
    for (int pw = 0; pw < 2; ++pw) {
      int wq = wo * 2 + pw;
      float s = 0.f;
      for (int ci = 0; ci < C2_; ++ci) {
        const float* yc = yb + ci * (H1_ * W1_);
#pragma unroll
        for (int kh = 0; kh < 3; ++kh) {
          int ih = h + kh - 1;
          if (ih < 0 || ih >= H1_) continue;
#pragma unroll
          for (int kw = 0; kw < 3; ++kw) {
            int iw = wq + kw - 1;
            if (iw < 0 || iw >= W1_) continue;
            s += yc[ih * W1_ + iw] * ws[((ci * 3 + kh) * 3 + kw) * C3_ + c];
          }
        }
      }
      m = fmaxf(m, s);
    }
  }
  x[n] = fmaxf(m + bias[c], 0.f);
}

// ---------------- gx GEMM: C[m][g] = bias[g] + dot(A[m][:K], W[g][:K]) -----
// A: [2560][640] row-major, W: [768][640] row-major
__global__ __launch_bounds__(256) void gemm_gx(
    const float* __restrict__ A, const float* __restrict__ W,
    const float* __restrict__ bias, float* __restrict__ C) {
  constexpr int K = IG_, N = G3_;
  __shared__ float As[16][64];
  __shared__ float Bs[16][64];
  int bm = blockIdx.x * 64, bn = blockIdx.y * 64;
  int tid  = threadIdx.x;
  int lrow = tid >> 2;          // 0..63
  int lk   = (tid & 3) * 4;     // 0,4,8,12
  int tm   = (tid >> 4) * 4;    // 0..60
  int tn   = (tid & 15) * 4;    // 0..60
  float acc[4][4] = {};
  for (int k0 = 0; k0 < K; k0 += 16) {
    float4 a4 = *(const float4*)(A + (size_t)(bm + lrow) * K + k0 + lk);
    float4 b4 = *(const float4*)(W + (size_t)(bn + lrow) * K + k0 + lk);
    As[lk + 0][lrow] = a4.x; As[lk + 1][lrow] = a4.y;
    As[lk + 2][lrow] = a4.z; As[lk + 3][lrow] = a4.w;
    Bs[lk + 0][lrow] = b4.x; Bs[lk + 1][lrow] = b4.y;
    Bs[lk + 2][lrow] = b4.z; Bs[lk + 3][lrow] = b4.w;
    __syncthreads();
#pragma unroll
    for (int k = 0; k < 16; ++k) {
      float4 av = *(const float4*)&As[k][tm];
      float4 bv = *(const float4*)&Bs[k][tn];
      float a[4] = {av.x, av.y, av.z, av.w};
      float b[4] = {bv.x, bv.y, bv.z, bv.w};
#pragma unroll
      for (int i = 0; i < 4; ++i)
#pragma unroll
        for (int j = 0; j < 4; ++j) acc[i][j] += a[i] * b[j];
    }
    __syncthreads();
  }
#pragma unroll
  for (int i = 0; i < 4; ++i)
#pragma unroll
    for (int j = 0; j < 4; ++j)
      C[(size_t)(bm + tm + i) * N + bn + tn + j] = acc[i][j] + bias[bn + tn + j];
}

// ---------------- persistent GRU: one block per (dir, batch-pair) ----------
__global__ __launch_bounds__(256) void gru_persist(
    const float* __restrict__ gx,      // [2][40][64][768], b_ih folded in
    const float* __restrict__ whh_f, const float* __restrict__ whh_b,
    const float* __restrict__ bhh_f, const float* __restrict__ bhh_b,
    const float* __restrict__ h0,      // [2][64][256]
    float* __restrict__ out) {
  int blk = blockIdx.x;            // 0..63
  int dir = blk >> 5;
  int b0  = (blk & 31) * 2;
  const float* Wr  = dir ? whh_b : whh_f;
  const float* bhh = dir ? bhh_b : bhh_f;
  __shared__ __align__(16) float h[2][HID_];
  __shared__ float gh[2][G3_];
  int tid = threadIdx.x;
  h[0][tid] = h0[(dir * 64 + b0 + 0) * HID_ + tid];
  h[1][tid] = h0[(dir * 64 + b0 + 1) * HID_ + tid];
  __syncthreads();
  for (int s = 0; s < T_; ++s) {
    int t = dir ? (T_ - 1 - s) : s;
    // phase 1: gh[bb][g] = h[bb] . Wr[g] + bhh[g]
#pragma unroll
    for (int gi = 0; gi < 3; ++gi) {
      int g = tid + gi * HID_;
      const float4* wrow = (const float4*)(Wr + (size_t)g * HID_);
      const float4* h0v  = (const float4*)h[0];
      const float4* h1v  = (const float4*)h[1];
      float acc0 = 0.f, acc1 = 0.f;
#pragma unroll 8
      for (int k4 = 0; k4 < HID_ / 4; ++k4) {
        float4 w4 = wrow[k4];
        float4 ha = h0v[k4];
        float4 hb = h1v[k4];
        acc0 += w4.x * ha.x + w4.y * ha.y + w4.z * ha.z + w4.w * ha.w;
        acc1 += w4.x * hb.x + w4.y * hb.y + w4.z * hb.z + w4.w * hb.w;
      }
      float bg = bhh[g];
      gh[0][g] = acc0 + bg;
      gh[1][g] = acc1 + bg;
    }
    __syncthreads();
    // phase 2: h_new
    const float* gxt = gx + ((size_t)(dir * T_ + t) * B_) * G3_;
#pragma unroll
    for (int bb = 0; bb < 2; ++bb) {
      int b = b0 + bb;
      const float* gxb = gxt + (size_t)b * G3_;
      float xr = gxb[tid], xz = gxb[HID_ + tid], xn = gxb[2 * HID_ + tid];
      float hr = gh[bb][tid], hz = gh[bb][HID_ + tid], hn = gh[bb][2 * HID_ + tid];
      float r = 1.f / (1.f + expf(-(xr + hr)));
      float z = 1.f / (1.f + expf(-(xz + hz)));
      float nn = tanhf(xn + r * hn);
      float hnew = (1.f - z) * nn + z * h[bb][tid];
      h[bb][tid] = hnew;
      out[((size_t)b * T_ + t) * (2 * HID_) + dir * HID_ + tid] = hnew;
    }
    __syncthreads();
  }
  out[OUT_MAIN_ + (size_t)(dir * 64 + b0 + 0) * HID_ + tid] = h[0][tid];
  out[OUT_MAIN_ + (size_t)(dir * 64 + b0 + 1) * HID_ + tid] = h[1][tid];
}

// ---------------- launch ----------------
extern "C" void kernel_launch(void* const* d_in, const int* in_sizes, int n_in,
                              void* d_out, int out_size, void* d_ws, size_t ws_size,
                              hipStream_t stream) {
  (void)in_sizes; (void)n_in; (void)out_size; (void)ws_size;
  const float* img    = (const float*)d_in[0];
  const float* hid0   = (const float*)d_in[1];
  const float* c0w    = (const float*)d_in[2];
  const float* c0b    = (const float*)d_in[3];
  const float* c1w    = (const float*)d_in[4];
  const float* c1b    = (const float*)d_in[5];
  const float* c2w    = (const float*)d_in[6];
  const float* c2b    = (const float*)d_in[7];
  const float* c3w    = (const float*)d_in[8];
  const float* c3b    = (const float*)d_in[9];
  const float* wih_f  = (const float*)d_in[10];
  const float* whh_f  = (const float*)d_in[11];
  const float* bih_f  = (const float*)d_in[12];
  const float* bhh_f  = (const float*)d_in[13];
  const float* wih_b  = (const float*)d_in[14];
  const float* whh_b  = (const float*)d_in[15];
  const float* bih_b  = (const float*)d_in[16];
  const float* bhh_b  = (const float*)d_in[17];
  float* out = (float*)d_out;

  // workspace layout (floats), peak 26,214,400 floats = 104.9 MB
  float* wsf = (float*)d_ws;
  float* y0 = wsf;                  // [0, 19,660,800)
  float* y2 = wsf + 19660800;       // [19,660,800, 26,214,400)
  float* y3 = wsf;                  // reuse y0: [0, 6,553,600)
  float* x  = wsf + 6553600;        // [6,553,600, 8,192,000)
  float* gx = wsf + 8192000;        // [8,192,000, 12,124,160)

  // conv0: 64*8*480*80 = 19,660,800 outputs
  conv0_relu<<<19660800 / 256, 256, 0, stream>>>(img, c0w, c0b, y0);
  // conv1+pool: 64*16*160*40 = 6,553,600 outputs
  conv1_relu_pool<<<6553600 / 256, 256, 0, stream>>>(y0, c1w, c1b, y2);
  // conv2: 6,553,600 outputs
  conv2_relu<<<6553600 / 256, 256, 0, stream>>>(y2, c2w, c2b, y3);
  // conv3+pool -> x (t,b,w,c): 40*64*20*32 = 1,638,400 outputs
  conv3_relu_pool<<<1638400 / 256, 256, 0, stream>>>(y3, c3w, c3b, x);
  // gx GEMMs: M=2560, N=768, K=640 per direction
  dim3 gg(T_ * B_ / 64, G3_ / 64);
  gemm_gx<<<gg, 256, 0, stream>>>(x, wih_f, bih_f, gx);
  gemm_gx<<<gg, 256, 0, stream>>>(x, wih_b, bih_b, gx + (size_t)T_ * B_ * G3_);
  // persistent GRU: 64 blocks (2 dirs x 32 batch-pairs)
  gru_persist<<<64, 256, 0, stream>>>(gx, whh_f, whh_b, bhh_f, bhh_b, hid0, out);
}

// Round 2
// 1410.612 us; speedup vs baseline: 2.6660x; 2.6660x over previous
//
#include <hip/hip_runtime.h>
#include <math.h>

// ---------------- problem dims ----------------
static constexpr int B_   = 64;
static constexpr int H0_  = 480, W0_ = 80;
static constexpr int C0_  = 8, C1_ = 16, C2_ = 16, C3_ = 32;
static constexpr int H1_  = 160, W1_ = 40;   // after pool1 (3,2)
static constexpr int T_   = 40,  WP_ = 20;   // after pool2 (4,2)
static constexpr int IG_  = 640;             // 20*32 GRU input
static constexpr int HID_ = 256;
static constexpr int G3_  = 768;             // 3*HID
static constexpr int OUT_MAIN_ = B_ * T_ * 2 * HID_;   // 1,310,720

// ======== fused conv0+relu + conv1+relu + maxpool(3,2) ========
// grid 64*20, block (b, r0): output rows [r0*8, r0*8+8), all 40 cols, 16 ch.
// LDS: img tile (28x82) + one y0 channel (26x82). Weights via scalar loads.
__global__ __launch_bounds__(320) void conv01_pool(
    const float* __restrict__ img, const float* __restrict__ w0,
    const float* __restrict__ b0, const float* __restrict__ w1,
    const float* __restrict__ b1, float* __restrict__ y2) {
  __shared__ float im[28 * 82];   // global rows r0*24-2 .. +25, cols -1..80
  __shared__ float y0c[26 * 82];  // one conv0 channel, rows r0*24-1 .. +24
  int b = blockIdx.x / 20, r0 = blockIdx.x % 20;
  int tid = threadIdx.x;
  const float* imgb = img + (size_t)b * (H0_ * W0_);

  for (int i = tid; i < 28 * 82; i += 320) {
    int r = i / 82, col = i % 82;
    int gr = r0 * 24 - 2 + r, gc = col - 1;
    float v = 0.f;
    if (gr >= 0 && gr < H0_ && gc >= 0 && gc < W0_) v = imgb[gr * W0_ + gc];
    im[i] = v;
  }
  __syncthreads();

  int oh_l = tid / 40, ow = tid % 40;  // 320 positions, one per thread
  float acc[6][16];
#pragma unroll
  for (int p = 0; p < 6; ++p)
#pragma unroll
    for (int c = 0; c < 16; ++c) acc[p][c] = 0.f;

#pragma unroll 1
  for (int ci = 0; ci < C0_; ++ci) {
    // ---- compute y0 channel ci into LDS ----
    float bci = b0[ci];
    for (int i = tid; i < 26 * 82; i += 320) {
      int r = i / 82, col = i % 82;
      int gr = r0 * 24 - 1 + r, gc = col - 1;
      float v = 0.f;
      if (gr >= 0 && gr < H0_ && gc >= 0 && gc < W0_) {
        float s = bci;
#pragma unroll
        for (int kh = 0; kh < 3; ++kh)
#pragma unroll
          for (int kw = 0; kw < 3; ++kw)
            s += im[(r + kh) * 82 + (col - 1 + kw)] * w0[(ci * 3 + kh) * 3 + kw];
        v = fmaxf(s, 0.f);
      }
      y0c[i] = v;
    }
    __syncthreads();
    // ---- accumulate conv1 for all 6 pool positions x 16 channels ----
    float rg[5][4];
#pragma unroll
    for (int rr = 0; rr < 5; ++rr) {
      const float2* rp = (const float2*)&y0c[(oh_l * 3 + rr) * 82 + 2 * ow];
      float2 u = rp[0], v = rp[1];
      rg[rr][0] = u.x; rg[rr][1] = u.y; rg[rr][2] = v.x; rg[rr][3] = v.y;
    }
#pragma unroll
    for (int c = 0; c < 16; ++c) {
#pragma unroll
      for (int kh = 0; kh < 3; ++kh)
#pragma unroll
        for (int kw = 0; kw < 3; ++kw) {
          float wv = w1[((c * C0_ + ci) * 3 + kh) * 3 + kw];  // uniform -> s_load
#pragma unroll
          for (int ph = 0; ph < 3; ++ph)
#pragma unroll
            for (int pw = 0; pw < 2; ++pw)
              acc[ph * 2 + pw][c] += rg[ph + kh][pw + kw] * wv;
        }
    }
    __syncthreads();
  }
#pragma unroll
  for (int c = 0; c < 16; ++c) {
    float m = acc[0][c];
#pragma unroll
    for (int p = 1; p < 6; ++p) m = fmaxf(m, acc[p][c]);
    y2[(((size_t)b * 16 + c) * 160 + r0 * 8 + oh_l) * 40 + ow] = fmaxf(m + b1[c], 0.f);
  }
}

// ======== conv2 (16->16) + relu, LDS tile ========
// grid 64*10, block (b, r0): output rows [r0*16, r0*16+16)
__global__ __launch_bounds__(320) void conv2_relu(
    const float* __restrict__ y2, const float* __restrict__ w2,
    const float* __restrict__ b2, float* __restrict__ y3) {
  __shared__ float t2[16 * 18 * 42];  // 12096 floats
  int b = blockIdx.x / 10, r0 = blockIdx.x % 10;
  int tid = threadIdx.x;
  const float* yb = y2 + (size_t)b * (16 * 160 * 40);
  for (int i = tid; i < 16 * 18 * 42; i += 320) {
    int col = i % 42; int r = (i / 42) % 18; int ci = i / (42 * 18);
    int gr = r0 * 16 - 1 + r, gc = col - 1;
    float v = 0.f;
    if (gr >= 0 && gr < 160 && gc >= 0 && gc < 40) v = yb[(ci * 160 + gr) * 40 + gc];
    t2[i] = v;
  }
  __syncthreads();
#pragma unroll 1
  for (int p = tid; p < 640; p += 320) {
    int oh = p / 40, ow = p % 40;
    float acc[16];
#pragma unroll
    for (int c = 0; c < 16; ++c) acc[c] = 0.f;
#pragma unroll 1
    for (int ci = 0; ci < 16; ++ci) {
      float pt[9];
#pragma unroll
      for (int kh = 0; kh < 3; ++kh)
#pragma unroll
        for (int kw = 0; kw < 3; ++kw)
          pt[kh * 3 + kw] = t2[(ci * 18 + oh + kh) * 42 + ow + kw];
#pragma unroll
      for (int c = 0; c < 16; ++c)
#pragma unroll
        for (int k = 0; k < 9; ++k)
          acc[c] += pt[k] * w2[(c * 16 + ci) * 9 + k];  // uniform -> s_load
    }
#pragma unroll
    for (int c = 0; c < 16; ++c)
      y3[(((size_t)b * 16 + c) * 160 + r0 * 16 + oh) * 40 + ow] = fmaxf(acc[c] + b2[c], 0.f);
  }
}

// ======== conv3 (16->32) + relu + maxpool(4,2), writes x[t][b][wo][c] ========
// grid 64*20, block (b, tp): t in {2tp, 2tp+1}
__global__ __launch_bounds__(320) void conv3_pool(
    const float* __restrict__ y3, const float* __restrict__ w3,
    const float* __restrict__ b3, float* __restrict__ x) {
  __shared__ float t3[16 * 10 * 42];  // 6720: rows 8tp-1..8tp+8, cols -1..40
  __shared__ float w3t[144 * 32];     // transposed: [k][c], lane-stride-1
  int b = blockIdx.x / 20, tp = blockIdx.x % 20;
  int tid = threadIdx.x;
  const float* yb = y3 + (size_t)b * (16 * 160 * 40);
  for (int i = tid; i < 16 * 10 * 42; i += 320) {
    int col = i % 42; int r = (i / 42) % 10; int ci = i / 420;
    int gr = tp * 8 - 1 + r, gc = col - 1;
    float v = 0.f;
    if (gr >= 0 && gr < 160 && gc >= 0 && gc < 40) v = yb[(ci * 160 + gr) * 40 + gc];
    t3[i] = v;
  }
  for (int i = tid; i < 144 * 32; i += 320) {
    int k = i / 32, c = i % 32;
    w3t[i] = w3[c * 144 + k];
  }
  __syncthreads();
#pragma unroll 1
  for (int it = 0; it < 4; ++it) {
    int wk = it * 320 + tid;  // 0..1279
    int c = wk & 31;
    int wo = (wk >> 5) % 20;
    int t2 = wk / 640;
    int t = tp * 2 + t2;
    float acc[8];
#pragma unroll
    for (int p = 0; p < 8; ++p) acc[p] = 0.f;
#pragma unroll 1
    for (int ci = 0; ci < 16; ++ci) {
      float rg[6][4];
#pragma unroll
      for (int rr = 0; rr < 6; ++rr) {
        const float2* rp = (const float2*)&t3[(ci * 10 + 4 * t2 + rr) * 42 + 2 * wo];
        float2 u = rp[0], v = rp[1];
        rg[rr][0] = u.x; rg[rr][1] = u.y; rg[rr][2] = v.x; rg[rr][3] = v.y;
      }
#pragma unroll
      for (int kh = 0; kh < 3; ++kh)
#pragma unroll
        for (int kw = 0; kw < 3; ++kw) {
          float wv = w3t[((ci * 3 + kh) * 3 + kw) * 32 + c];
#pragma unroll
          for (int ph = 0; ph < 4; ++ph)
#pragma unroll
            for (int pw = 0; pw < 2; ++pw)
              acc[ph * 2 + pw] += rg[ph + kh][pw + kw] * wv;
        }
    }
    float m = acc[0];
#pragma unroll
    for (int p = 1; p < 8; ++p) m = fmaxf(m, acc[p]);
    x[(((size_t)t * 64 + b) * 20 + wo) * 32 + c] = fmaxf(m + b3[c], 0.f);
  }
}

// ---------------- gx GEMM: C[m][g] = bias[g] + dot(A[m][:K], W[g][:K]) -----
__global__ __launch_bounds__(256) void gemm_gx(
    const float* __restrict__ A, const float* __restrict__ W,
    const float* __restrict__ bias, float* __restrict__ C) {
  constexpr int K = IG_, N = G3_;
  __shared__ float As[16][64];
  __shared__ float Bs[16][64];
  int bm = blockIdx.x * 64, bn = blockIdx.y * 64;
  int tid  = threadIdx.x;
  int lrow = tid >> 2;
  int lk   = (tid & 3) * 4;
  int tm   = (tid >> 4) * 4;
  int tn   = (tid & 15) * 4;
  float acc[4][4] = {};
  for (int k0 = 0; k0 < K; k0 += 16) {
    float4 a4 = *(const float4*)(A + (size_t)(bm + lrow) * K + k0 + lk);
    float4 b4 = *(const float4*)(W + (size_t)(bn + lrow) * K + k0 + lk);
    As[lk + 0][lrow] = a4.x; As[lk + 1][lrow] = a4.y;
    As[lk + 2][lrow] = a4.z; As[lk + 3][lrow] = a4.w;
    Bs[lk + 0][lrow] = b4.x; Bs[lk + 1][lrow] = b4.y;
    Bs[lk + 2][lrow] = b4.z; Bs[lk + 3][lrow] = b4.w;
    __syncthreads();
#pragma unroll
    for (int k = 0; k < 16; ++k) {
      float4 av = *(const float4*)&As[k][tm];
      float4 bv = *(const float4*)&Bs[k][tn];
      float a[4] = {av.x, av.y, av.z, av.w};
      float bb[4] = {bv.x, bv.y, bv.z, bv.w};
#pragma unroll
      for (int i = 0; i < 4; ++i)
#pragma unroll
        for (int j = 0; j < 4; ++j) acc[i][j] += a[i] * bb[j];
    }
    __syncthreads();
  }
#pragma unroll
  for (int i = 0; i < 4; ++i)
#pragma unroll
    for (int j = 0; j < 4; ++j)
      C[(size_t)(bm + tm + i) * N + bn + tn + j] = acc[i][j] + bias[bn + tn + j];
}

// ---------------- persistent GRU: one block per (dir, batch-pair) ----------
__global__ __launch_bounds__(256) void gru_persist(
    const float* __restrict__ gx,
    const float* __restrict__ whh_f, const float* __restrict__ whh_b,
    const float* __restrict__ bhh_f, const float* __restrict__ bhh_b,
    const float* __restrict__ h0,
    float* __restrict__ out) {
  int blk = blockIdx.x;
  int dir = blk >> 5;
  int b0  = (blk & 31) * 2;
  const float* Wr  = dir ? whh_b : whh_f;
  const float* bhh = dir ? bhh_b : bhh_f;
  __shared__ __align__(16) float h[2][HID_];
  __shared__ float gh[2][G3_];
  int tid = threadIdx.x;
  h[0][tid] = h0[(dir * 64 + b0 + 0) * HID_ + tid];
  h[1][tid] = h0[(dir * 64 + b0 + 1) * HID_ + tid];
  __syncthreads();
  for (int s = 0; s < T_; ++s) {
    int t = dir ? (T_ - 1 - s) : s;
#pragma unroll
    for (int gi = 0; gi < 3; ++gi) {
      int g = tid + gi * HID_;
      const float4* wrow = (const float4*)(Wr + (size_t)g * HID_);
      const float4* h0v  = (const float4*)h[0];
      const float4* h1v  = (const float4*)h[1];
      float acc0 = 0.f, acc1 = 0.f;
#pragma unroll 8
      for (int k4 = 0; k4 < HID_ / 4; ++k4) {
        float4 w4 = wrow[k4];
        float4 ha = h0v[k4];
        float4 hb = h1v[k4];
        acc0 += w4.x * ha.x + w4.y * ha.y + w4.z * ha.z + w4.w * ha.w;
        acc1 += w4.x * hb.x + w4.y * hb.y + w4.z * hb.z + w4.w * hb.w;
      }
      float bg = bhh[g];
      gh[0][g] = acc0 + bg;
      gh[1][g] = acc1 + bg;
    }
    __syncthreads();
    const float* gxt = gx + ((size_t)(dir * T_ + t) * B_) * G3_;
#pragma unroll
    for (int bb = 0; bb < 2; ++bb) {
      int b = b0 + bb;
      const float* gxb = gxt + (size_t)b * G3_;
      float xr = gxb[tid], xz = gxb[HID_ + tid], xn = gxb[2 * HID_ + tid];
      float hr = gh[bb][tid], hz = gh[bb][HID_ + tid], hn = gh[bb][2 * HID_ + tid];
      float r = 1.f / (1.f + expf(-(xr + hr)));
      float z = 1.f / (1.f + expf(-(xz + hz)));
      float nn = tanhf(xn + r * hn);
      float hnew = (1.f - z) * nn + z * h[bb][tid];
      h[bb][tid] = hnew;
      out[((size_t)b * T_ + t) * (2 * HID_) + dir * HID_ + tid] = hnew;
    }
    __syncthreads();
  }
  out[OUT_MAIN_ + (size_t)(dir * 64 + b0 + 0) * HID_ + tid] = h[0][tid];
  out[OUT_MAIN_ + (size_t)(dir * 64 + b0 + 1) * HID_ + tid] = h[1][tid];
}

// ---------------- launch ----------------
extern "C" void kernel_launch(void* const* d_in, const int* in_sizes, int n_in,
                              void* d_out, int out_size, void* d_ws, size_t ws_size,
                              hipStream_t stream) {
  (void)in_sizes; (void)n_in; (void)out_size; (void)ws_size;
  const float* img    = (const float*)d_in[0];
  const float* hid0   = (const float*)d_in[1];
  const float* c0w    = (const float*)d_in[2];
  const float* c0b    = (const float*)d_in[3];
  const float* c1w    = (const float*)d_in[4];
  const float* c1b    = (const float*)d_in[5];
  const float* c2w    = (const float*)d_in[6];
  const float* c2b    = (const float*)d_in[7];
  const float* c3w    = (const float*)d_in[8];
  const float* c3b    = (const float*)d_in[9];
  const float* wih_f  = (const float*)d_in[10];
  const float* whh_f  = (const float*)d_in[11];
  const float* bih_f  = (const float*)d_in[12];
  const float* bhh_f  = (const float*)d_in[13];
  const float* wih_b  = (const float*)d_in[14];
  const float* whh_b  = (const float*)d_in[15];
  const float* bih_b  = (const float*)d_in[16];
  const float* bhh_b  = (const float*)d_in[17];
  float* out = (float*)d_out;

  // workspace layout (floats): y2[6.55M] y3[6.55M] x[1.64M] gx[3.93M] = 74.7 MB
  float* wsf = (float*)d_ws;
  float* y2 = wsf;
  float* y3 = wsf + 6553600;
  float* x  = wsf + 13107200;
  float* gx = wsf + 14745600;

  conv01_pool<<<64 * 20, 320, 0, stream>>>(img, c0w, c0b, c1w, c1b, y2);
  conv2_relu<<<64 * 10, 320, 0, stream>>>(y2, c2w, c2b, y3);
  conv3_pool<<<64 * 20, 320, 0, stream>>>(y3, c3w, c3b, x);
  dim3 gg(T_ * B_ / 64, G3_ / 64);
  gemm_gx<<<gg, 256, 0, stream>>>(x, wih_f, bih_f, gx);
  gemm_gx<<<gg, 256, 0, stream>>>(x, wih_b, bih_b, gx + (size_t)T_ * B_ * G3_);
  gru_persist<<<64, 256, 0, stream>>>(gx, whh_f, whh_b, bhh_f, bhh_b, hid0, out);
}

// Round 3
// 671.293 us; speedup vs baseline: 5.6022x; 2.1013x over previous
//
#include <hip/hip_runtime.h>
#include <math.h>

// ---------------- problem dims ----------------
static constexpr int B_   = 64;
static constexpr int H0_  = 480, W0_ = 80;
static constexpr int C0_  = 8, C1_ = 16, C2_ = 16, C3_ = 32;
static constexpr int H1_  = 160, W1_ = 40;   // after pool1 (3,2)
static constexpr int T_   = 40,  WP_ = 20;   // after pool2 (4,2)
static constexpr int IG_  = 640;             // 20*32 GRU input
static constexpr int HID_ = 256;
static constexpr int G3_  = 768;             // 3*HID
static constexpr int OUT_MAIN_ = B_ * T_ * 2 * HID_;   // 1,310,720

typedef __attribute__((ext_vector_type(8))) short bf16x8;
typedef __attribute__((ext_vector_type(4))) float f32x4;

__device__ inline short f2bf(float f) {
  unsigned u = __builtin_bit_cast(unsigned, f);
  u = (u + 0x7FFFu + ((u >> 16) & 1u)) >> 16;
  return (short)u;
}
__device__ inline float sigm_(float x) { return 1.f / (1.f + __expf(-x)); }
__device__ inline float tanh_(float x) { return 1.f - 2.f / (1.f + __expf(2.f * x)); }

// ======== fused conv0+relu + conv1+relu + maxpool(3,2) ========
__global__ __launch_bounds__(320) void conv01_pool(
    const float* __restrict__ img, const float* __restrict__ w0,
    const float* __restrict__ b0, const float* __restrict__ w1,
    const float* __restrict__ b1, float* __restrict__ y2) {
  __shared__ float im[28 * 82];
  __shared__ float y0c[26 * 82];
  int b = blockIdx.x / 20, r0 = blockIdx.x % 20;
  int tid = threadIdx.x;
  const float* imgb = img + (size_t)b * (H0_ * W0_);

  for (int i = tid; i < 28 * 82; i += 320) {
    int r = i / 82, col = i % 82;
    int gr = r0 * 24 - 2 + r, gc = col - 1;
    float v = 0.f;
    if (gr >= 0 && gr < H0_ && gc >= 0 && gc < W0_) v = imgb[gr * W0_ + gc];
    im[i] = v;
  }
  __syncthreads();

  int oh_l = tid / 40, ow = tid % 40;
  float acc[6][16];
#pragma unroll
  for (int p = 0; p < 6; ++p)
#pragma unroll
    for (int c = 0; c < 16; ++c) acc[p][c] = 0.f;

#pragma unroll 1
  for (int ci = 0; ci < C0_; ++ci) {
    float bci = b0[ci];
    for (int i = tid; i < 26 * 82; i += 320) {
      int r = i / 82, col = i % 82;
      int gr = r0 * 24 - 1 + r, gc = col - 1;
      float v = 0.f;
      if (gr >= 0 && gr < H0_ && gc >= 0 && gc < W0_) {
        float s = bci;
#pragma unroll
        for (int kh = 0; kh < 3; ++kh)
#pragma unroll
          for (int kw = 0; kw < 3; ++kw)
            s += im[(r + kh) * 82 + (col - 1 + kw)] * w0[(ci * 3 + kh) * 3 + kw];
        v = fmaxf(s, 0.f);
      }
      y0c[i] = v;
    }
    __syncthreads();
    float rg[5][4];
#pragma unroll
    for (int rr = 0; rr < 5; ++rr) {
      const float2* rp = (const float2*)&y0c[(oh_l * 3 + rr) * 82 + 2 * ow];
      float2 u = rp[0], v = rp[1];
      rg[rr][0] = u.x; rg[rr][1] = u.y; rg[rr][2] = v.x; rg[rr][3] = v.y;
    }
#pragma unroll
    for (int c = 0; c < 16; ++c) {
#pragma unroll
      for (int kh = 0; kh < 3; ++kh)
#pragma unroll
        for (int kw = 0; kw < 3; ++kw) {
          float wv = w1[((c * C0_ + ci) * 3 + kh) * 3 + kw];
#pragma unroll
          for (int ph = 0; ph < 3; ++ph)
#pragma unroll
            for (int pw = 0; pw < 2; ++pw)
              acc[ph * 2 + pw][c] += rg[ph + kh][pw + kw] * wv;
        }
    }
    __syncthreads();
  }
#pragma unroll
  for (int c = 0; c < 16; ++c) {
    float m = acc[0][c];
#pragma unroll
    for (int p = 1; p < 6; ++p) m = fmaxf(m, acc[p][c]);
    y2[(((size_t)b * 16 + c) * 160 + r0 * 8 + oh_l) * 40 + ow] = fmaxf(m + b1[c], 0.f);
  }
}

// ======== conv2 (16->16) + relu ========
__global__ __launch_bounds__(320) void conv2_relu(
    const float* __restrict__ y2, const float* __restrict__ w2,
    const float* __restrict__ b2, float* __restrict__ y3) {
  __shared__ float t2[16 * 18 * 42];
  int b = blockIdx.x / 10, r0 = blockIdx.x % 10;
  int tid = threadIdx.x;
  const float* yb = y2 + (size_t)b * (16 * 160 * 40);
  for (int i = tid; i < 16 * 18 * 42; i += 320) {
    int col = i % 42; int r = (i / 42) % 18; int ci = i / (42 * 18);
    int gr = r0 * 16 - 1 + r, gc = col - 1;
    float v = 0.f;
    if (gr >= 0 && gr < 160 && gc >= 0 && gc < 40) v = yb[(ci * 160 + gr) * 40 + gc];
    t2[i] = v;
  }
  __syncthreads();
#pragma unroll 1
  for (int p = tid; p < 640; p += 320) {
    int oh = p / 40, ow = p % 40;
    float acc[16];
#pragma unroll
    for (int c = 0; c < 16; ++c) acc[c] = 0.f;
#pragma unroll 1
    for (int ci = 0; ci < 16; ++ci) {
      float pt[9];
#pragma unroll
      for (int kh = 0; kh < 3; ++kh)
#pragma unroll
        for (int kw = 0; kw < 3; ++kw)
          pt[kh * 3 + kw] = t2[(ci * 18 + oh + kh) * 42 + ow + kw];
#pragma unroll
      for (int c = 0; c < 16; ++c)
#pragma unroll
        for (int k = 0; k < 9; ++k)
          acc[c] += pt[k] * w2[(c * 16 + ci) * 9 + k];
    }
#pragma unroll
    for (int c = 0; c < 16; ++c)
      y3[(((size_t)b * 16 + c) * 160 + r0 * 16 + oh) * 40 + ow] = fmaxf(acc[c] + b2[c], 0.f);
  }
}

// ======== conv3 (16->32) + relu + maxpool(4,2), writes x[t][b][wo][c] ========
__global__ __launch_bounds__(320) void conv3_pool(
    const float* __restrict__ y3, const float* __restrict__ w3,
    const float* __restrict__ b3, float* __restrict__ x) {
  __shared__ float t3[16 * 10 * 42];
  __shared__ float w3t[144 * 32];
  int b = blockIdx.x / 20, tp = blockIdx.x % 20;
  int tid = threadIdx.x;
  const float* yb = y3 + (size_t)b * (16 * 160 * 40);
  for (int i = tid; i < 16 * 10 * 42; i += 320) {
    int col = i % 42; int r = (i / 42) % 10; int ci = i / 420;
    int gr = tp * 8 - 1 + r, gc = col - 1;
    float v = 0.f;
    if (gr >= 0 && gr < 160 && gc >= 0 && gc < 40) v = yb[(ci * 160 + gr) * 40 + gc];
    t3[i] = v;
  }
  for (int i = tid; i < 144 * 32; i += 320) {
    int k = i / 32, c = i % 32;
    w3t[i] = w3[c * 144 + k];
  }
  __syncthreads();
#pragma unroll 1
  for (int it = 0; it < 4; ++it) {
    int wk = it * 320 + tid;
    int c = wk & 31;
    int wo = (wk >> 5) % 20;
    int t2 = wk / 640;
    int t = tp * 2 + t2;
    float acc[8];
#pragma unroll
    for (int p = 0; p < 8; ++p) acc[p] = 0.f;
#pragma unroll 1
    for (int ci = 0; ci < 16; ++ci) {
      float rg[6][4];
#pragma unroll
      for (int rr = 0; rr < 6; ++rr) {
        const float2* rp = (const float2*)&t3[(ci * 10 + 4 * t2 + rr) * 42 + 2 * wo];
        float2 u = rp[0], v = rp[1];
        rg[rr][0] = u.x; rg[rr][1] = u.y; rg[rr][2] = v.x; rg[rr][3] = v.y;
      }
#pragma unroll
      for (int kh = 0; kh < 3; ++kh)
#pragma unroll
        for (int kw = 0; kw < 3; ++kw) {
          float wv = w3t[((ci * 3 + kh) * 3 + kw) * 32 + c];
#pragma unroll
          for (int ph = 0; ph < 4; ++ph)
#pragma unroll
            for (int pw = 0; pw < 2; ++pw)
              acc[ph * 2 + pw] += rg[ph + kh][pw + kw] * wv;
        }
    }
    float m = acc[0];
#pragma unroll
    for (int p = 1; p < 8; ++p) m = fmaxf(m, acc[p]);
    x[(((size_t)t * 64 + b) * 20 + wo) * 32 + c] = fmaxf(m + b3[c], 0.f);
  }
}

// ---------------- gx GEMM (fp32, unchanged) ----------------
__global__ __launch_bounds__(256) void gemm_gx(
    const float* __restrict__ A, const float* __restrict__ W,
    const float* __restrict__ bias, float* __restrict__ C) {
  constexpr int K = IG_, N = G3_;
  __shared__ float As[16][64];
  __shared__ float Bs[16][64];
  int bm = blockIdx.x * 64, bn = blockIdx.y * 64;
  int tid  = threadIdx.x;
  int lrow = tid >> 2;
  int lk   = (tid & 3) * 4;
  int tm   = (tid >> 4) * 4;
  int tn   = (tid & 15) * 4;
  float acc[4][4] = {};
  for (int k0 = 0; k0 < K; k0 += 16) {
    float4 a4 = *(const float4*)(A + (size_t)(bm + lrow) * K + k0 + lk);
    float4 b4 = *(const float4*)(W + (size_t)(bn + lrow) * K + k0 + lk);
    As[lk + 0][lrow] = a4.x; As[lk + 1][lrow] = a4.y;
    As[lk + 2][lrow] = a4.z; As[lk + 3][lrow] = a4.w;
    Bs[lk + 0][lrow] = b4.x; Bs[lk + 1][lrow] = b4.y;
    Bs[lk + 2][lrow] = b4.z; Bs[lk + 3][lrow] = b4.w;
    __syncthreads();
#pragma unroll
    for (int k = 0; k < 16; ++k) {
      float4 av = *(const float4*)&As[k][tm];
      float4 bv = *(const float4*)&Bs[k][tn];
      float a[4] = {av.x, av.y, av.z, av.w};
      float bb[4] = {bv.x, bv.y, bv.z, bv.w};
#pragma unroll
      for (int i = 0; i < 4; ++i)
#pragma unroll
        for (int j = 0; j < 4; ++j) acc[i][j] += a[i] * bb[j];
    }
    __syncthreads();
  }
#pragma unroll
  for (int i = 0; i < 4; ++i)
#pragma unroll
    for (int j = 0; j < 4; ++j)
      C[(size_t)(bm + tm + i) * N + bn + tn + j] = acc[i][j] + bias[bn + tn + j];
}

// ======== weight-stationary MFMA GRU ========
// 8 blocks: (dir, 16-batch group). 1024 threads = 16 waves; wave w owns
// hidden slice j in [16w, 16w+16). r/z weights: persistent bf16 B-fragments
// in VGPRs (64/lane). n weights: bf16 in LDS (135 KB). h: bf16 in LDS,
// padded stride 264 shorts (2-way bank aliasing only = free).
__global__ __launch_bounds__(1024) void gru_mfma(
    const float* __restrict__ gx,
    const float* __restrict__ whh_f, const float* __restrict__ whh_b,
    const float* __restrict__ bhh_f, const float* __restrict__ bhh_b,
    const float* __restrict__ h0, float* __restrict__ out) {
  constexpr int HP = 264;               // padded row stride (shorts)
  __shared__ short wn[256 * HP];        // n-gate weights bf16: 135,168 B
  __shared__ short hlds[16 * HP];       // h bf16: 8,448 B   (total 143.6 KB)
  int blk = blockIdx.x, dir = blk >> 2, mb = blk & 3;
  const float* Wh  = dir ? whh_b : whh_f;
  const float* bhh = dir ? bhh_b : bhh_f;
  int tid = threadIdx.x;
  int wave = tid >> 6, lane = tid & 63, q = lane >> 4, n = lane & 15;
  int jw = wave << 4;

  // ---- n-gate weights -> LDS (4 threads/row, 64 cols each) ----
  {
    int r = tid >> 2, c0 = (tid & 3) * 64;
    const float* src = Wh + (size_t)(512 + r) * HID_ + c0;
    short* dst = &wn[r * HP + c0];
#pragma unroll
    for (int c = 0; c < 64; c += 4) {
      float4 v = *(const float4*)(src + c);
      dst[c + 0] = f2bf(v.x); dst[c + 1] = f2bf(v.y);
      dst[c + 2] = f2bf(v.z); dst[c + 3] = f2bf(v.w);
    }
  }
  // ---- h -> LDS bf16 (16 local batches x 256) ----
  {
    int r = tid >> 6, c0 = (tid & 63) * 4;
    const float* src = h0 + (size_t)(dir * 64 + mb * 16 + r) * HID_ + c0;
    float4 v = *(const float4*)src;
    short* dst = &hlds[r * HP + c0];
    dst[0] = f2bf(v.x); dst[1] = f2bf(v.y); dst[2] = f2bf(v.z); dst[3] = f2bf(v.w);
  }
  // ---- r,z weight fragments in registers ----
  // B-frag layout: lane(q,n) holds B[k=kt*32+q*8+j][col=n] = Wh[row][k...]
  bf16x8 Br[8], Bz[8];
#pragma unroll
  for (int kt = 0; kt < 8; ++kt) {
    const float* pr = Wh + (size_t)(jw + n) * HID_ + kt * 32 + q * 8;
    const float* pz = Wh + (size_t)(256 + jw + n) * HID_ + kt * 32 + q * 8;
    float4 u = *(const float4*)pr, v = *(const float4*)(pr + 4);
    Br[kt] = (bf16x8){f2bf(u.x), f2bf(u.y), f2bf(u.z), f2bf(u.w),
                      f2bf(v.x), f2bf(v.y), f2bf(v.z), f2bf(v.w)};
    float4 uz = *(const float4*)pz, vz = *(const float4*)(pz + 4);
    Bz[kt] = (bf16x8){f2bf(uz.x), f2bf(uz.y), f2bf(uz.z), f2bf(uz.w),
                      f2bf(vz.x), f2bf(vz.y), f2bf(vz.z), f2bf(vz.w)};
  }
  // h_old fp32 slice: lane(q,n) owns batches q*4+r, col jw+n (matches C-layout)
  float hold[4];
#pragma unroll
  for (int r = 0; r < 4; ++r)
    hold[r] = h0[(size_t)(dir * 64 + mb * 16 + q * 4 + r) * HID_ + jw + n];
  float bh0 = bhh[jw + n], bh1 = bhh[256 + jw + n], bh2 = bhh[512 + jw + n];
  __syncthreads();

  for (int s = 0; s < T_; ++s) {
    int t = dir ? (T_ - 1 - s) : s;
    // prefetch gx for this step (independent of h -> hides L2 latency)
    const float* gxt = gx + ((size_t)(dir * T_ + t) * B_ + mb * 16) * G3_;
    float xr[4], xz[4], xn[4];
#pragma unroll
    for (int r = 0; r < 4; ++r) {
      const float* gxb = gxt + (size_t)(q * 4 + r) * G3_ + jw + n;
      xr[r] = gxb[0]; xz[r] = gxb[256]; xn[r] = gxb[512];
    }
    // phase 1: gh = h @ Wh^T  (M=16 batch, N=16 j-slice x 3 gates, K=256)
    f32x4 a0 = {0.f, 0.f, 0.f, 0.f}, a1 = a0, a2 = a0;
#pragma unroll
    for (int kt = 0; kt < 8; ++kt) {
      bf16x8 af = *(const bf16x8*)&hlds[n * HP + kt * 32 + q * 8];   // A[m=n][k]
      bf16x8 bn = *(const bf16x8*)&wn[(jw + n) * HP + kt * 32 + q * 8];
      a0 = __builtin_amdgcn_mfma_f32_16x16x32_bf16(af, Br[kt], a0, 0, 0, 0);
      a1 = __builtin_amdgcn_mfma_f32_16x16x32_bf16(af, Bz[kt], a1, 0, 0, 0);
      a2 = __builtin_amdgcn_mfma_f32_16x16x32_bf16(af, bn, a2, 0, 0, 0);
    }
    __syncthreads();   // all hlds reads done before phase-2 writes
    // phase 2: gates + h update. C-layout: lane(q,n) reg r -> batch q*4+r, col jw+n
#pragma unroll
    for (int r = 0; r < 4; ++r) {
      int bl = q * 4 + r;
      float rg = sigm_(xr[r] + a0[r] + bh0);
      float zg = sigm_(xz[r] + a1[r] + bh1);
      float ng = tanh_(xn[r] + rg * (a2[r] + bh2));
      float hnew = (1.f - zg) * ng + zg * hold[r];
      hold[r] = hnew;
      int gb = mb * 16 + bl;
      out[((size_t)gb * T_ + t) * (2 * HID_) + dir * HID_ + jw + n] = hnew;
      hlds[bl * HP + jw + n] = f2bf(hnew);
    }
    __syncthreads();   // h writes visible before next step's reads
  }
#pragma unroll
  for (int r = 0; r < 4; ++r)
    out[(size_t)OUT_MAIN_ + (size_t)(dir * 64 + mb * 16 + q * 4 + r) * HID_ + jw + n] = hold[r];
}

// ---------------- launch ----------------
extern "C" void kernel_launch(void* const* d_in, const int* in_sizes, int n_in,
                              void* d_out, int out_size, void* d_ws, size_t ws_size,
                              hipStream_t stream) {
  (void)in_sizes; (void)n_in; (void)out_size; (void)ws_size;
  const float* img    = (const float*)d_in[0];
  const float* hid0   = (const float*)d_in[1];
  const float* c0w    = (const float*)d_in[2];
  const float* c0b    = (const float*)d_in[3];
  const float* c1w    = (const float*)d_in[4];
  const float* c1b    = (const float*)d_in[5];
  const float* c2w    = (const float*)d_in[6];
  const float* c2b    = (const float*)d_in[7];
  const float* c3w    = (const float*)d_in[8];
  const float* c3b    = (const float*)d_in[9];
  const float* wih_f  = (const float*)d_in[10];
  const float* whh_f  = (const float*)d_in[11];
  const float* bih_f  = (const float*)d_in[12];
  const float* bhh_f  = (const float*)d_in[13];
  const float* wih_b  = (const float*)d_in[14];
  const float* whh_b  = (const float*)d_in[15];
  const float* bih_b  = (const float*)d_in[16];
  const float* bhh_b  = (const float*)d_in[17];
  float* out = (float*)d_out;

  float* wsf = (float*)d_ws;
  float* y2 = wsf;
  float* y3 = wsf + 6553600;
  float* x  = wsf + 13107200;
  float* gx = wsf + 14745600;

  conv01_pool<<<64 * 20, 320, 0, stream>>>(img, c0w, c0b, c1w, c1b, y2);
  conv2_relu<<<64 * 10, 320, 0, stream>>>(y2, c2w, c2b, y3);
  conv3_pool<<<64 * 20, 320, 0, stream>>>(y3, c3w, c3b, x);
  dim3 gg(T_ * B_ / 64, G3_ / 64);
  gemm_gx<<<gg, 256, 0, stream>>>(x, wih_f, bih_f, gx);
  gemm_gx<<<gg, 256, 0, stream>>>(x, wih_b, bih_b, gx + (size_t)T_ * B_ * G3_);
  gru_mfma<<<8, 1024, 0, stream>>>(gx, whh_f, whh_b, bhh_f, bhh_b, hid0, out);
}